// Round 7
// baseline (440.631 us; speedup 1.0000x reference)
//
#include <hip/hip_runtime.h>
#include <hip/hip_bf16.h>

typedef __attribute__((ext_vector_type(8))) short short8;
typedef __attribute__((ext_vector_type(4))) float floatx4;

__device__ __forceinline__ ushort f2bf(float x) {
    __hip_bfloat16 h = __float2bfloat16(x);
    return __builtin_bit_cast(ushort, h);
}
__device__ __forceinline__ float bf2f(ushort u) {
    __hip_bfloat16 h = __builtin_bit_cast(__hip_bfloat16, u);
    return __bfloat162float(h);
}

// fast tanh: 1 - 2/(e^{2z}+1); v_exp + v_rcp, ~1e-6 abs err
__device__ __forceinline__ float fast_tanh(float z) {
    float e = __expf(2.0f * z);
    return 1.0f - 2.0f * __builtin_amdgcn_rcpf(e + 1.0f);
}

// async global -> LDS, 16 bytes per lane. LDS dest is wave-uniform base + lane*16;
// per-lane GLOBAL source is arbitrary (exploited for the XOR bank swizzle).
__device__ __forceinline__ void gload_lds16(const ushort* g, ushort* l) {
    __builtin_amdgcn_global_load_lds(
        (const __attribute__((address_space(1))) unsigned int*)(const void*)g,
        (__attribute__((address_space(3))) unsigned int*)(void*)l,
        16, 0, 0);
}

// ---------------------------------------------------------------------------
// Fused prep (one dispatch):
//   bid <  1024: grid-stride h0 pack, 16 items/thread, 32B load -> 16B store.
//                (round-6 prep used 1 float4/thread over 32768 tiny blocks:
//                 latency-bound, ~110 us. This shape is BW-bound.)
//   bid >= 1024: 32x32 weight-transpose tiles (Wf, W1, W2), one tile/block.
// ---------------------------------------------------------------------------
__global__ void prep(const float* __restrict__ inp, const float* __restrict__ hz,
                     const float* __restrict__ Wf, const float* __restrict__ W1,
                     const float* __restrict__ W2,
                     ushort* __restrict__ h0, ushort* __restrict__ WfT,
                     ushort* __restrict__ W1T, ushort* __restrict__ W2T) {
    const int bid = blockIdx.x;
    const int tid = threadIdx.x;
    __shared__ float tile[32][33];
    if (bid < 1024) {
        // items of 8 fp32 -> 8 bf16; h0 row = j>>7, col8 = (j&127)*8
        const int nItems = 32768 * 128;
        const int stride = 1024 * 256;
        for (int j = bid * 256 + tid; j < nItems; j += stride) {
            size_t row = (size_t)(j >> 7);
            int col = (j & 127) * 8;
            const float* src = (col < 512) ? (inp + row * 512 + col)
                                           : (hz + row * 512 + (col - 512));
            float4 v0 = *(const float4*)src;
            float4 v1 = *(const float4*)(src + 4);
            short8 o;
            o[0] = (short)f2bf(v0.x); o[1] = (short)f2bf(v0.y);
            o[2] = (short)f2bf(v0.z); o[3] = (short)f2bf(v0.w);
            o[4] = (short)f2bf(v1.x); o[5] = (short)f2bf(v1.y);
            o[6] = (short)f2bf(v1.z); o[7] = (short)f2bf(v1.w);
            *(short8*)(h0 + row * 1024 + col) = o;
        }
    } else {
        int t = bid - 1024;
        const float* W;
        ushort* WT;
        int N = 1024;
        if (t < 1024)      { W = Wf; WT = WfT; }
        else if (t < 2048) { W = W1; WT = W1T; t -= 1024; }
        else               { W = W2; WT = W2T; t -= 2048; N = 512; }
        int tx = tid & 31, ty = tid >> 5;
        int nb = (t % (N / 32)) * 32, kb = (t / (N / 32)) * 32;
        #pragma unroll
        for (int j = ty; j < 32; j += 8)
            tile[j][tx] = W[(size_t)(kb + j) * N + nb + tx];
        __syncthreads();
        #pragma unroll
        for (int j = ty; j < 32; j += 8)
            WT[(size_t)(nb + j) * 1024 + kb + tx] = f2bf(tile[tx][j]);
    }
}

// ---------------------------------------------------------------------------
// 128(M)x256(N)-tile bf16 MFMA GEMM, 512 threads / 8 waves, BK=64 (two 32-k
// panels per barrier — halves the vmcnt(0) barrier-drain count vs BK=32).
// A [M][1024] bf16 row-major, BT [NOUT][1024] bf16 (W transposed).
// MODE 1: out_bf = bf2f(A[row][col]) + 0.1*tanh(acc + bias)   (euler step)
// MODE 2: out_bf = relu(acc + bias)
// MODE 3: out_f32 = tanh(acc + bias)
// Grid 1-D: xcd=id&7 owns M-tiles [xcd*32, xcd*32+32); N-tiles innermost.
// Regs: 64 VGPR + 64 AGPR = 128/wave exactly -> 4 waves/SIMD, 2 blocks/CU.
// ---------------------------------------------------------------------------
template <int MODE, int NOUT, int NX>
__global__ __launch_bounds__(512, 4) void gemm_ep(
    const ushort* __restrict__ A, const ushort* __restrict__ BT,
    const float* __restrict__ bias,
    ushort* __restrict__ outB, float* __restrict__ outF) {
    constexpr int K = 1024;
    __shared__ ushort As[2][128 * 32];   // 16 KB (two 32-k panels)
    __shared__ ushort Bs[2][256 * 32];   // 32 KB

    const int tid = threadIdx.x;
    const int wave = tid >> 6, lane = tid & 63;

    const int id = blockIdx.x;
    const int inner = id >> 3;
    const int nTile = inner % NX;
    const int mTile = (id & 7) * 32 + inner / NX;
    const int mBase = mTile * 128;
    const int nBase = nTile * 256;
    const int waveM = wave >> 2;      // 0..1  (64-row band)
    const int waveN = wave & 3;       // 0..3  (64-col band)

    // Per-panel staging with XOR bank swizzle (measured zero-conflict):
    // physical 16B slot c holds logical (row r=c>>2, quad q=(c&3)^((r>>1)&3)).
    const int ca = wave * 64 + lane;
    const int ra = ca >> 2;
    const int qa = (ca & 3) ^ ((ra >> 1) & 3);
    const ushort* agA = A + (size_t)(mBase + ra) * K + qa * 8;
    const ushort* bg0 = BT + (size_t)(nBase + ra) * K + qa * 8;
    const ushort* bg1 = BT + (size_t)(nBase + ra + 128) * K + qa * 8;
    ushort* asD  = &As[0][0] + (size_t)(wave * 64) * 8;
    ushort* bsD0 = &Bs[0][0] + (size_t)(wave * 64) * 8;
    ushort* bsD1 = &Bs[0][0] + (size_t)(wave * 64 + 512) * 8;

    floatx4 acc[4][4];
    #pragma unroll
    for (int i = 0; i < 4; i++)
        #pragma unroll
        for (int j = 0; j < 4; j++) acc[i][j] = (floatx4)(0.f);

    const int mrow = lane & 15;
    const int g = lane >> 4;                  // logical k-quad
    const int pq = g ^ ((mrow >> 1) & 3);     // physical quad
    const int kqOff = pq * 8;

    for (int k0 = 0; k0 < K; k0 += 64) {
        // panel 0 (k0..k0+31) and panel 1 (k0+32..k0+63); one barrier for both
        gload_lds16(agA + k0,      asD);
        gload_lds16(bg0 + k0,      bsD0);
        gload_lds16(bg1 + k0,      bsD1);
        gload_lds16(agA + k0 + 32, asD + 128 * 32);
        gload_lds16(bg0 + k0 + 32, bsD0 + 256 * 32);
        gload_lds16(bg1 + k0 + 32, bsD1 + 256 * 32);
        __syncthreads();

        #pragma unroll
        for (int p = 0; p < 2; p++) {
            short8 af[4], bfr[4];
            #pragma unroll
            for (int t = 0; t < 4; t++) {
                af[t]  = *(const short8*)(&As[p][0] + (waveM * 64 + t * 16 + mrow) * 32 + kqOff);
                bfr[t] = *(const short8*)(&Bs[p][0] + (waveN * 64 + t * 16 + mrow) * 32 + kqOff);
            }
            #pragma unroll
            for (int mt = 0; mt < 4; mt++)
                #pragma unroll
                for (int nt = 0; nt < 4; nt++)
                    acc[mt][nt] = __builtin_amdgcn_mfma_f32_16x16x32_bf16(
                        af[mt], bfr[nt], acc[mt][nt], 0, 0, 0);
        }
        __syncthreads();
    }

    // epilogue: C/D layout col=lane&15, row=(lane>>4)*4+reg  [m89/m91]
    const int col0 = nBase + waveN * 64 + (lane & 15);
    const int row0 = mBase + waveM * 64 + (lane >> 4) * 4;
    #pragma unroll
    for (int mt = 0; mt < 4; mt++) {
        #pragma unroll
        for (int nt = 0; nt < 4; nt++) {
            const int col = col0 + nt * 16;
            const float bv = bias[col];
            #pragma unroll
            for (int r = 0; r < 4; r++) {
                const int row = row0 + mt * 16 + r;
                const float z = acc[mt][nt][r] + bv;
                if (MODE == 1) {
                    float carry = bf2f(A[(size_t)row * K + col]);
                    outB[(size_t)row * NOUT + col] = f2bf(carry + 0.1f * fast_tanh(z));
                } else if (MODE == 2) {
                    outB[(size_t)row * NOUT + col] = f2bf(fmaxf(z, 0.f));
                } else {
                    outF[(size_t)row * NOUT + col] = fast_tanh(z);
                }
            }
        }
    }
}

extern "C" void kernel_launch(void* const* d_in, const int* in_sizes, int n_in,
                              void* d_out, int out_size, void* d_ws, size_t ws_size,
                              hipStream_t stream) {
    const float* inp = (const float*)d_in[0];  // [32,1024,512]
    const float* hz  = (const float*)d_in[1];  // [32,1024,512]
    const float* Wf  = (const float*)d_in[2];  // [1024,1024]
    const float* bf_ = (const float*)d_in[3];  // [1024]
    const float* W1  = (const float*)d_in[4];  // [1024,1024]
    const float* b1  = (const float*)d_in[5];  // [1024]
    const float* W2  = (const float*)d_in[6];  // [1024,512]
    const float* b2  = (const float*)d_in[7];  // [512]
    float* out = (float*)d_out;                // [32,1024,512] fp32

    char* ws = (char*)d_ws;
    ushort* WfT  = (ushort*)(ws);                                  // 2 MB
    ushort* W1T  = (ushort*)(ws + (size_t)(2 << 20));              // 2 MB
    ushort* W2T  = (ushort*)(ws + (size_t)(4 << 20));              // 1 MB
    ushort* bufA = (ushort*)(ws + (size_t)(8 << 20));              // 64 MB
    ushort* bufB = (ushort*)(ws + (size_t)(8 << 20) + ((size_t)64 << 20));  // 64 MB

    // fused prep: fat grid-stride pack (1024 blocks) + 2560 transpose tiles
    prep<<<1024 + 2560, 256, 0, stream>>>(inp, hz, Wf, W1, W2, bufA, WfT, W1T, W2T);

    // h1 = h0 + 0.1*tanh(h0@Wf + bf)
    gemm_ep<1, 1024, 4><<<1024, 512, 0, stream>>>(bufA, WfT, bf_, bufB, nullptr);
    // h2 = h1 + 0.1*tanh(h1@Wf + bf)
    gemm_ep<1, 1024, 4><<<1024, 512, 0, stream>>>(bufB, WfT, bf_, bufA, nullptr);
    // g = relu(h2@W1 + b1)
    gemm_ep<2, 1024, 4><<<1024, 512, 0, stream>>>(bufA, W1T, b1, bufB, nullptr);
    // out = tanh(g@W2 + b2)
    gemm_ep<3, 512, 2><<<512, 512, 0, stream>>>(bufB, W2T, b2, nullptr, out);
}